// Round 19
// baseline (521.124 us; speedup 1.0000x reference)
//
#include <hip/hip_runtime.h>
#include <math.h>

// ---- problem constants (match reference) ----
#define BB 8
#define N_GO 12000
#define N_GENES 20000
#define IN_F 8
#define FF 64
#define D_ATT 5
#define L_DIM 16
#define N_LAST 4000
#define P0_ 4000
#define EPSF 1e-5f

__device__ __forceinline__ unsigned bf16_rne(float f) {
    unsigned u = __float_as_uint(f);
    return (u + 0x7fffu + ((u >> 16) & 1u)) >> 16;
}

// ============================================================
// row bounds via binary search on sorted src: rs[r]=lb(r), re[r]=lb(r+1)
__global__ void k_bounds_bs(const int* __restrict__ src, int* __restrict__ rs,
                            int* __restrict__ re, int E, int n) {
    int r = blockIdx.x * 256 + threadIdx.x;
    if (r >= n) return;
    int lo = 0, hi = E;
    while (lo < hi) { int m = (lo + hi) >> 1; if (src[m] < r) lo = m + 1; else hi = m; }
    rs[r] = lo;
    int lo2 = lo, hi2 = E;
    while (lo2 < hi2) { int m = (lo2 + hi2) >> 1; if (src[m] < r + 1) lo2 = m + 1; else hi2 = m; }
    re[r] = lo2;
}

// data (B, N_GENES) -> dataT (N_GENES, B)
__global__ void k_tr_data(const float* __restrict__ data, float* __restrict__ dataT) {
    int idx = blockIdx.x * 256 + threadIdx.x;
    if (idx >= N_GENES * BB) return;
    int g = idx >> 3, b = idx & 7;
    dataT[idx] = data[b * N_GENES + g];
}

// wave per GO row: lanes = 8 edge-slots x 8 features; dataT broadcast loads
__global__ void k_gene2go_w(const float* __restrict__ dataT, const float* __restrict__ t,
                            const int* __restrict__ col, const int* __restrict__ rs,
                            const int* __restrict__ re, float* __restrict__ x0, int nnz) {
    int wid = blockIdx.x * 4 + (threadIdx.x >> 6);
    if (wid >= N_GO) return;
    int lane = threadIdx.x & 63;
    int f = lane & 7, eo = lane >> 3;
    int e0 = rs[wid], e1 = re[wid];
    float acc[BB];
#pragma unroll
    for (int b = 0; b < BB; b++) acc[b] = 0.f;
    for (int e = e0; e < e1; e += 8) {
        int ee = e + eo;
        bool ok = ee < e1;
        int ec = ok ? ee : (e1 - 1);
        int c = col[ec];
        float tv = ok ? t[(size_t)f * nnz + ee] : 0.f;
        const float4* dt = (const float4*)(dataT + (size_t)c * 8);
        float4 d0 = dt[0], d1 = dt[1];
        acc[0] += tv * d0.x; acc[1] += tv * d0.y; acc[2] += tv * d0.z; acc[3] += tv * d0.w;
        acc[4] += tv * d1.x; acc[5] += tv * d1.y; acc[6] += tv * d1.z; acc[7] += tv * d1.w;
    }
#pragma unroll
    for (int b = 0; b < BB; b++) {
        acc[b] += __shfl_xor(acc[b], 8);
        acc[b] += __shfl_xor(acc[b], 16);
        acc[b] += __shfl_xor(acc[b], 32);
    }
    if (lane < IN_F) {
#pragma unroll
        for (int b = 0; b < BB; b++)
            x0[((size_t)b * N_GO + wid) * IN_F + lane] = acc[b];
    }
}

// dual linear FIN=8 (enc0): weights tiny, both matrices in regs (pinned)
template<bool SCAL>
__global__ __launch_bounds__(256, 2)
void k_linear2_att8(const float* __restrict__ X, const float* __restrict__ W1,
                    const float* __restrict__ W2, const float* __restrict__ watt,
                    const float* __restrict__ ws, float* __restrict__ Y1,
                    float* __restrict__ Y2, float* __restrict__ ASRC,
                    float* __restrict__ ADST, float* __restrict__ VS,
                    int n_nodes, long xbs, int xoff, int total_waves) {
    __shared__ float w1s[IN_F * 65];
    __shared__ float w2s[IN_F * 65];
    int lane = threadIdx.x & 63;
    for (int i = threadIdx.x; i < IN_F * FF; i += 256) {
        int fo = i >> 3, k = i & 7;          // W row-major [fo][k]
        w1s[k * 65 + fo] = W1[i];
        w2s[k * 65 + fo] = W2[i];
    }
    __syncthreads();
    float w1r[IN_F], w2r[IN_F];
#pragma unroll
    for (int k = 0; k < IN_F; k++) {
        w1r[k] = w1s[k * 65 + lane];
        w2r[k] = w2s[k * 65 + lane];
        asm volatile("" : "+v"(w1r[k]));
        asm volatile("" : "+v"(w2r[k]));
    }
    float wa = 0.f, wb = 0.f, wc = 0.f;
    if (SCAL) { wa = watt[lane]; wb = watt[FF + lane]; wc = ws[lane]; }
    int wid = blockIdx.x * 4 + (threadIdx.x >> 6);
    for (int n = wid; n < n_nodes; n += total_waves) {
        for (int b = 0; b < BB; b++) {
            const float* xr = X + (size_t)b * xbs + (size_t)(n + xoff) * IN_F;
            float4 x0 = *(const float4*)xr, x1 = *(const float4*)(xr + 4);
            float a1 = x0.x * w1r[0] + x0.y * w1r[1] + x0.z * w1r[2] + x0.w * w1r[3]
                     + x1.x * w1r[4] + x1.y * w1r[5] + x1.z * w1r[6] + x1.w * w1r[7];
            float a2 = x0.x * w2r[0] + x0.y * w2r[1] + x0.z * w2r[2] + x0.w * w2r[3]
                     + x1.x * w2r[4] + x1.y * w2r[5] + x1.z * w2r[6] + x1.w * w2r[7];
            Y1[((size_t)b * n_nodes + n) * FF + lane] = a1;
            Y2[((size_t)b * n_nodes + n) * FF + lane] = a2;
            if (SCAL) {
                float s0 = a1 * wa, s1 = a1 * wb, s2 = a2 * wc;
                for (int m = 1; m < 64; m <<= 1) {
                    s0 += __shfl_xor(s0, m);
                    s1 += __shfl_xor(s1, m);
                    s2 += __shfl_xor(s2, m);
                }
                if (lane == 0) {
                    ASRC[b * n_nodes + n] = s0;
                    ADST[b * n_nodes + n] = s1;
                    VS[b * n_nodes + n] = 1.f / (1.f + expf(-s2));
                }
            }
        }
    }
}

// dual linear FIN=64 FOUT=64: weights packed 2xbf16 per VGPR (pinned) ->
// 64 weight regs instead of 128 -> 2 blocks/CU occupancy.
template<bool SCAL>
__global__ __launch_bounds__(256, 2)
void k_lin64d(const float* __restrict__ X, const float* __restrict__ W1,
              const float* __restrict__ W2, const float* __restrict__ watt,
              const float* __restrict__ ws, float* __restrict__ Y1,
              float* __restrict__ Y2, float* __restrict__ ASRC,
              float* __restrict__ ADST, float* __restrict__ VS,
              int n_nodes, long xbs, int xoff, int total_waves) {
    __shared__ float w1s[FF * 65];
    __shared__ float w2s[FF * 65];
    int lane = threadIdx.x & 63;
    for (int i = threadIdx.x; i < FF * FF; i += 256) {
        int fo = i >> 6, k = i & 63;
        w1s[fo * 65 + k] = W1[i];
        w2s[fo * 65 + k] = W2[i];
    }
    __syncthreads();
    unsigned w1p[FF / 2], w2p[FF / 2];
#pragma unroll
    for (int j = 0; j < FF / 2; j++) {
        w1p[j] = (bf16_rne(w1s[lane * 65 + 2 * j + 1]) << 16) | bf16_rne(w1s[lane * 65 + 2 * j]);
        w2p[j] = (bf16_rne(w2s[lane * 65 + 2 * j + 1]) << 16) | bf16_rne(w2s[lane * 65 + 2 * j]);
        asm volatile("" : "+v"(w1p[j]));
        asm volatile("" : "+v"(w2p[j]));
    }
    float wa = 0.f, wb = 0.f, wc = 0.f;
    if (SCAL) { wa = watt[lane]; wb = watt[FF + lane]; wc = ws[lane]; }
    int wid = blockIdx.x * 4 + (threadIdx.x >> 6);
    for (int n = wid; n < n_nodes; n += total_waves) {
        for (int b = 0; b < BB; b++) {
            const float* xr = X + (size_t)b * xbs + (size_t)(n + xoff) * FF;
            float a1 = 0.f, a2 = 0.f;
#pragma unroll
            for (int k = 0; k < FF; k += 4) {
                float4 x = *(const float4*)(xr + k);
                unsigned q10 = w1p[k >> 1], q11 = w1p[(k >> 1) + 1];
                unsigned q20 = w2p[k >> 1], q21 = w2p[(k >> 1) + 1];
                a1 += x.x * __uint_as_float(q10 << 16)
                    + x.y * __uint_as_float(q10 & 0xffff0000u)
                    + x.z * __uint_as_float(q11 << 16)
                    + x.w * __uint_as_float(q11 & 0xffff0000u);
                a2 += x.x * __uint_as_float(q20 << 16)
                    + x.y * __uint_as_float(q20 & 0xffff0000u)
                    + x.z * __uint_as_float(q21 << 16)
                    + x.w * __uint_as_float(q21 & 0xffff0000u);
            }
            Y1[((size_t)b * n_nodes + n) * FF + lane] = a1;
            Y2[((size_t)b * n_nodes + n) * FF + lane] = a2;
            if (SCAL) {
                float s0 = a1 * wa, s1 = a1 * wb, s2 = a2 * wc;
                for (int m = 1; m < 64; m <<= 1) {
                    s0 += __shfl_xor(s0, m);
                    s1 += __shfl_xor(s1, m);
                    s2 += __shfl_xor(s2, m);
                }
                if (lane == 0) {
                    ASRC[b * n_nodes + n] = s0;
                    ADST[b * n_nodes + n] = s1;
                    VS[b * n_nodes + n] = 1.f / (1.f + expf(-s2));
                }
            }
        }
    }
}

// dual linear FIN=64 FOUT=8 (dec1): packed bf16 weights, 8 node-slots/wave
__global__ __launch_bounds__(256, 2)
void k_lin8d(const float* __restrict__ X, const float* __restrict__ W1,
             const float* __restrict__ W2, float* __restrict__ Y1,
             float* __restrict__ Y2, int n_nodes, long xbs, int xoff,
             int total_waves) {
    __shared__ float w1s[IN_F * 65];
    __shared__ float w2s[IN_F * 65];
    int lane = threadIdx.x & 63;
    for (int i = threadIdx.x; i < IN_F * FF; i += 256) {
        int fo = i >> 6, k = i & 63;
        w1s[fo * 65 + k] = W1[i];
        w2s[fo * 65 + k] = W2[i];
    }
    __syncthreads();
    int of = lane & 7;
    int slot = lane >> 3;
    unsigned w1p[FF / 2], w2p[FF / 2];
#pragma unroll
    for (int j = 0; j < FF / 2; j++) {
        w1p[j] = (bf16_rne(w1s[of * 65 + 2 * j + 1]) << 16) | bf16_rne(w1s[of * 65 + 2 * j]);
        w2p[j] = (bf16_rne(w2s[of * 65 + 2 * j + 1]) << 16) | bf16_rne(w2s[of * 65 + 2 * j]);
        asm volatile("" : "+v"(w1p[j]));
        asm volatile("" : "+v"(w2p[j]));
    }
    int wid = blockIdx.x * 4 + (threadIdx.x >> 6);
    for (long n0 = (long)wid * 8; n0 < n_nodes; n0 += (long)total_waves * 8) {
        int n = (int)n0 + slot;
        bool ok = (n < n_nodes);
        int nn = ok ? n : (n_nodes - 1);
        for (int b = 0; b < BB; b++) {
            const float* xr = X + (size_t)b * xbs + (size_t)(nn + xoff) * FF;
            float a1 = 0.f, a2 = 0.f;
#pragma unroll
            for (int k = 0; k < FF; k += 4) {
                float4 x = *(const float4*)(xr + k);
                unsigned q10 = w1p[k >> 1], q11 = w1p[(k >> 1) + 1];
                unsigned q20 = w2p[k >> 1], q21 = w2p[(k >> 1) + 1];
                a1 += x.x * __uint_as_float(q10 << 16)
                    + x.y * __uint_as_float(q10 & 0xffff0000u)
                    + x.z * __uint_as_float(q11 << 16)
                    + x.w * __uint_as_float(q11 & 0xffff0000u);
                a2 += x.x * __uint_as_float(q20 << 16)
                    + x.y * __uint_as_float(q20 & 0xffff0000u)
                    + x.z * __uint_as_float(q21 << 16)
                    + x.w * __uint_as_float(q21 & 0xffff0000u);
            }
            if (ok) {
                Y1[((size_t)b * n_nodes + n) * IN_F + of] = a1;
                Y2[((size_t)b * n_nodes + n) * IN_F + of] = a2;
            }
        }
    }
}

// v[b,e] = exp(tanh(a_src[b,src[e]] + a_dst[b,dst[e]]))  (fully parallel)
__global__ void k_edge_v(const float* __restrict__ a_src, const float* __restrict__ a_dst,
                         const int* __restrict__ src, const int* __restrict__ dst,
                         float* __restrict__ v, int E, int n_nodes) {
    int e = blockIdx.x * 256 + threadIdx.x;
    if (e >= E) return;
    int b = blockIdx.y;
    v[(size_t)b * E + e] = expf(tanhf(a_src[b * n_nodes + src[e]] + a_dst[b * n_nodes + dst[e]]));
}

// fused encoder aggregation: XCD-pinned batch, wave per row, x4-unrolled gather,
// precomputed edge weights, LN stats fused.  (R13-proven form)
__global__ void k_agg_enc_f(const float* __restrict__ Xin, const float* __restrict__ Xs,
                            const float* __restrict__ EDGEV, const float* __restrict__ VS,
                            const int* __restrict__ dst, const int* __restrict__ rs,
                            const int* __restrict__ re, float* __restrict__ Out,
                            float* __restrict__ sums, int n_nodes, int E, int nblk) {
    int b = blockIdx.x & 7;
    int wid = threadIdx.x >> 6;
    int lane = threadIdx.x & 63;
    const float* Xb  = Xin + (size_t)b * n_nodes * FF;
    const float* Xsb = Xs  + (size_t)b * n_nodes * FF;
    const float* vv  = EDGEV + (size_t)b * E;
    float s1 = 0.f, s2 = 0.f;
    for (int r = (blockIdx.x >> 3) * 4 + wid; r < n_nodes; r += nblk * 4) {
        int e0 = rs[r], e1 = re[r];
        float sv0 = 0.f, sv1 = 0.f, sv2 = 0.f, sv3 = 0.f;
        float acc0 = 0.f, acc1 = 0.f, acc2 = 0.f, acc3 = 0.f;
        int e = e0;
        for (; e + 3 < e1; e += 4) {
            int d0 = dst[e], d1 = dst[e + 1], d2 = dst[e + 2], d3 = dst[e + 3];
            float v0 = vv[e], v1 = vv[e + 1], v2 = vv[e + 2], v3 = vv[e + 3];
            sv0 += v0; sv1 += v1; sv2 += v2; sv3 += v3;
            acc0 += v0 * Xb[(size_t)d0 * FF + lane];
            acc1 += v1 * Xb[(size_t)d1 * FF + lane];
            acc2 += v2 * Xb[(size_t)d2 * FF + lane];
            acc3 += v3 * Xb[(size_t)d3 * FF + lane];
        }
        for (; e < e1; e++) {
            int d0 = dst[e];
            float v0 = vv[e];
            sv0 += v0;
            acc0 += v0 * Xb[(size_t)d0 * FF + lane];
        }
        float sv = (sv0 + sv1) + (sv2 + sv3);
        float acc = (acc0 + acc1) + (acc2 + acc3);
        float o = (e1 > e0) ? acc / sv : 0.f;
        o += Xsb[(size_t)r * FF + lane] * VS[b * n_nodes + r];
        Out[((size_t)b * n_nodes + r) * FF + lane] = o;
        s1 += o; s2 += o * o;
    }
    __shared__ float sh1[4][64], sh2[4][64];
    sh1[wid][lane] = s1; sh2[wid][lane] = s2;
    __syncthreads();
    if (wid == 0) {
        float a = sh1[0][lane] + sh1[1][lane] + sh1[2][lane] + sh1[3][lane];
        float c = sh2[0][lane] + sh2[1][lane] + sh2[2][lane] + sh2[3][lane];
        atomicAdd(&sums[(b * FF + lane) * 2],     a);
        atomicAdd(&sums[(b * FF + lane) * 2 + 1], c);
    }
}

// LN over node axis: accumulate sum & sumsq per (b,f)  (used for Fdim=8 only)
__global__ void k_ln_stats(const float* __restrict__ X, float* __restrict__ sums,
                           int n_nodes, int Fdim, int npb) {
    int b = blockIdx.y;
    int f = threadIdx.x & (Fdim - 1);
    int nl = threadIdx.x / Fdim;
    int stride = 256 / Fdim;
    int n0 = blockIdx.x * npb;
    int n1 = n0 + npb; if (n1 > n_nodes) n1 = n_nodes;
    const float* xb = X + (size_t)b * n_nodes * Fdim;
    float s1 = 0.f, s2 = 0.f;
    for (int n = n0 + nl; n < n1; n += stride) {
        float x = xb[(size_t)n * Fdim + f];
        s1 += x; s2 += x * x;
    }
    __shared__ float sh1[256], sh2[256];
    sh1[threadIdx.x] = s1; sh2[threadIdx.x] = s2;
    __syncthreads();
    for (int o = 128; o >= Fdim; o >>= 1) {
        if (threadIdx.x < o) { sh1[threadIdx.x] += sh1[threadIdx.x + o]; sh2[threadIdx.x] += sh2[threadIdx.x + o]; }
        __syncthreads();
    }
    if (threadIdx.x < Fdim) {
        atomicAdd(&sums[(b * Fdim + threadIdx.x) * 2],     sh1[threadIdx.x]);
        atomicAdd(&sums[(b * Fdim + threadIdx.x) * 2 + 1], sh2[threadIdx.x]);
    }
}

// Y = relu((X - mu)*rsqrt(var+eps)*g[n] + bb[n])
__global__ void k_ln_apply_relu(const float* __restrict__ X, const float* __restrict__ sums,
                                const float* __restrict__ g, const float* __restrict__ bb,
                                float* __restrict__ Y, int n_nodes, int Fdim) {
    long idx = (long)blockIdx.x * 256 + threadIdx.x;
    if (idx >= (long)n_nodes * Fdim) return;
    int b = blockIdx.y;
    int n = (int)(idx / Fdim);
    int f = (int)(idx % Fdim);
    float s1 = sums[(b * Fdim + f) * 2], s2 = sums[(b * Fdim + f) * 2 + 1];
    float mu = s1 / n_nodes;
    float var = s2 / n_nodes - mu * mu;
    float rs = rsqrtf(var + EPSF);
    size_t o = (size_t)b * n_nodes * Fdim + idx;
    float y = (X[o] - mu) * rs * g[n] + bb[n];
    Y[o] = fmaxf(y, 0.f);
}

// int degree histogram
__global__ void k_deg_i(const int* __restrict__ src, int* __restrict__ deg, int E) {
    int e = blockIdx.x * 256 + threadIdx.x;
    if (e < E) atomicAdd(&deg[src[e]], 1);
}

// single-block exclusive scan: rsd[0..n] prefix, cursor copy
__global__ void k_scan(const int* __restrict__ deg, int* __restrict__ rsd,
                       int* __restrict__ cursor, int n) {
    __shared__ int part[1024];
    int t = threadIdx.x;
    int chunk = (n + 1023) >> 10;
    int s0 = t * chunk, s1 = s0 + chunk; if (s1 > n) s1 = n;
    int s = 0;
    for (int i = s0; i < s1 && i < n; i++) s += deg[i];
    part[t] = s;
    __syncthreads();
    for (int o = 1; o < 1024; o <<= 1) {
        int v = (t >= o) ? part[t - o] : 0;
        __syncthreads();
        part[t] += v;
        __syncthreads();
    }
    int base = (t == 0) ? 0 : part[t - 1];
    for (int i = s0; i < s1 && i < n; i++) {
        rsd[i] = base; cursor[i] = base;
        base += deg[i];
    }
    if (t == 1023) rsd[n] = part[1023];
}

// scatter dst into CSR order
__global__ void k_scatter(const int* __restrict__ src, const int* __restrict__ dst,
                          int* __restrict__ cursor, int* __restrict__ csrd, int E) {
    int e = blockIdx.x * 256 + threadIdx.x;
    if (e >= E) return;
    int pos = atomicAdd(&cursor[src[e]], 1);
    csrd[pos] = dst[e];
}

// scatter (row, tD) into column-CSR order
__global__ void k_scatter2(const int* __restrict__ key, const int* __restrict__ row,
                           const float* __restrict__ tD, int* __restrict__ cursor,
                           int* __restrict__ csrr, float* __restrict__ csrt, int E) {
    int e = blockIdx.x * 256 + threadIdx.x;
    if (e >= E) return;
    int pos = atomicAdd(&cursor[key[e]], 1);
    csrr[pos] = row[e];
    csrt[pos] = tD[e];
}

// x_D gather: wave per gene, lane = (slot<<3)|batch; reduce over 8 slots
__global__ void k_xd_g(const float* __restrict__ outD, const int* __restrict__ rsg,
                       const int* __restrict__ csrr, const float* __restrict__ csrt,
                       float* __restrict__ xD) {
    int g = blockIdx.x * 4 + (threadIdx.x >> 6);
    if (g >= N_GENES) return;
    int lane = threadIdx.x & 63;
    int b = lane & 7, slot = lane >> 3;
    int e0 = rsg[g], e1 = rsg[g + 1];
    float acc = 0.f;
    for (int e = e0 + slot; e < e1; e += 8)
        acc += csrt[e] * outD[(size_t)b * N_GO + csrr[e]];
    acc += __shfl_xor(acc, 8);
    acc += __shfl_xor(acc, 16);
    acc += __shfl_xor(acc, 32);
    if (lane < BB)
        xD[(size_t)b * N_GENES + g] = acc;
}

// decoder aggregation F=64: XCD-pinned batch, CSR gather x4-unrolled, LN fused
__global__ void k_agg_dec64(const float* __restrict__ Xout, const float* __restrict__ Xs,
                            const int* __restrict__ rsd, const int* __restrict__ csrd,
                            float* __restrict__ Out, float* __restrict__ sums,
                            int n_rows, int n_in, int offset, int nblk) {
    int b = blockIdx.x & 7;
    int wid = threadIdx.x >> 6;
    int lane = threadIdx.x & 63;
    const float* Xb = Xout + (size_t)b * n_in * FF;
    int nxs = n_rows - offset;
    const float* Xsb = Xs + (size_t)b * nxs * FF;
    float s1 = 0.f, s2 = 0.f;
    for (int r = (blockIdx.x >> 3) * 4 + wid; r < n_rows; r += nblk * 4) {
        int e0 = rsd[r], e1 = rsd[r + 1];
        float acc0 = 0.f, acc1 = 0.f, acc2 = 0.f, acc3 = 0.f;
        int e = e0;
        for (; e + 3 < e1; e += 4) {
            acc0 += Xb[(size_t)csrd[e] * FF + lane];
            acc1 += Xb[(size_t)csrd[e + 1] * FF + lane];
            acc2 += Xb[(size_t)csrd[e + 2] * FF + lane];
            acc3 += Xb[(size_t)csrd[e + 3] * FF + lane];
        }
        for (; e < e1; e++) acc0 += Xb[(size_t)csrd[e] * FF + lane];
        float acc = (acc0 + acc1) + (acc2 + acc3);
        float o = (e1 > e0) ? acc / (float)(e1 - e0) : 0.f;
        if (r >= offset)
            o += Xsb[(size_t)(r - offset) * FF + lane];
        Out[((size_t)b * n_rows + r) * FF + lane] = o;
        s1 += o; s2 += o * o;
    }
    __shared__ float sh1[4][64], sh2[4][64];
    sh1[wid][lane] = s1; sh2[wid][lane] = s2;
    __syncthreads();
    if (wid == 0) {
        float a = sh1[0][lane] + sh1[1][lane] + sh1[2][lane] + sh1[3][lane];
        float c = sh2[0][lane] + sh2[1][lane] + sh2[2][lane] + sh2[3][lane];
        atomicAdd(&sums[(b * FF + lane) * 2],     a);
        atomicAdd(&sums[(b * FF + lane) * 2 + 1], c);
    }
}

// decoder aggregation F=8: 8 edge-slots x 8 features per wave
__global__ void k_agg_dec8(const float* __restrict__ Xout, const float* __restrict__ Xs,
                           const int* __restrict__ rsd, const int* __restrict__ csrd,
                           float* __restrict__ Out, int n_rows, int n_in, int offset) {
    int r = blockIdx.x * 4 + (threadIdx.x >> 6);
    if (r >= n_rows) return;
    int lane = threadIdx.x & 63;
    int f = lane & 7, slot = lane >> 3;
    int e0 = rsd[r], e1 = rsd[r + 1];
    float acc[BB];
#pragma unroll
    for (int b = 0; b < BB; b++) acc[b] = 0.f;
    for (int e = e0 + slot; e < e1; e += 8) {
        int d = csrd[e];
#pragma unroll
        for (int b = 0; b < BB; b++)
            acc[b] += Xout[((size_t)b * n_in + d) * IN_F + f];
    }
#pragma unroll
    for (int b = 0; b < BB; b++) {
        acc[b] += __shfl_xor(acc[b], 8);
        acc[b] += __shfl_xor(acc[b], 16);
        acc[b] += __shfl_xor(acc[b], 32);
    }
    float coef = (e1 > e0) ? 1.f / (float)(e1 - e0) : 0.f;
    int nxs = n_rows - offset;
    if (lane < IN_F) {
#pragma unroll
        for (int b = 0; b < BB; b++) {
            float o = acc[b] * coef;
            if (r >= offset)
                o += Xs[((size_t)b * nxs + (r - offset)) * IN_F + lane];
            Out[((size_t)b * n_rows + r) * IN_F + lane] = o;
        }
    }
}

// fused heads: wave per node. catt (5 outs, BN over b,d) + conc (1 out, BN over b)
__global__ void k_heads(const float* __restrict__ X, const float* __restrict__ Wa,
                        const float* __restrict__ wc, const float* __restrict__ ga,
                        const float* __restrict__ ba, const float* __restrict__ gc,
                        const float* __restrict__ bc, float* __restrict__ ATT,
                        float* __restrict__ INP, long xbs, int xoff) {
    int i = blockIdx.x * 4 + (threadIdx.x >> 6);
    if (i >= N_LAST) return;
    int lane = threadIdx.x & 63;
    float w0 = Wa[0 * FF + lane], w1 = Wa[1 * FF + lane], w2 = Wa[2 * FF + lane];
    float w3 = Wa[3 * FF + lane], w4 = Wa[4 * FF + lane];
    float wcv = wc[lane];
    float y[BB][D_ATT], yc[BB];
    float s1 = 0.f, s2 = 0.f;
#pragma unroll
    for (int b = 0; b < BB; b++) {
        float x = X[(size_t)b * xbs + (size_t)(i + xoff) * FF + lane];
        float p0 = x * w0, p1 = x * w1, p2 = x * w2, p3 = x * w3, p4 = x * w4, pc = x * wcv;
        for (int m = 1; m < 64; m <<= 1) {
            p0 += __shfl_xor(p0, m); p1 += __shfl_xor(p1, m); p2 += __shfl_xor(p2, m);
            p3 += __shfl_xor(p3, m); p4 += __shfl_xor(p4, m); pc += __shfl_xor(pc, m);
        }
        y[b][0] = p0; y[b][1] = p1; y[b][2] = p2; y[b][3] = p3; y[b][4] = p4;
        yc[b] = pc;
        s1 += p0 + p1 + p2 + p3 + p4;
        s2 += p0 * p0 + p1 * p1 + p2 * p2 + p3 * p3 + p4 * p4;
    }
    const float cnt = (float)(BB * D_ATT);
    float mu = s1 / cnt, var = s2 / cnt - mu * mu;
    float rsv = rsqrtf(var + EPSF);
    float gg = ga[i], bv = ba[i];
#pragma unroll
    for (int b = 0; b < BB; b++) {
        float yv = lane == 0 ? y[b][0] : lane == 1 ? y[b][1] : lane == 2 ? y[b][2]
                 : lane == 3 ? y[b][3] : y[b][4];
        if (lane < D_ATT)
            ATT[((size_t)b * N_LAST + i) * D_ATT + lane] = fmaxf((yv - mu) * rsv * gg + bv, 0.f);
    }
    float c1 = 0.f, c2 = 0.f;
#pragma unroll
    for (int b = 0; b < BB; b++) { c1 += yc[b]; c2 += yc[b] * yc[b]; }
    float muc = c1 / BB, varc = c2 / BB - muc * muc;
    float rc = rsqrtf(varc + EPSF);
    float ggc = gc[i], bvc = bc[i];
    if (lane < BB) {
        float v = lane == 0 ? yc[0] : lane == 1 ? yc[1] : lane == 2 ? yc[2] : lane == 3 ? yc[3]
                : lane == 4 ? yc[4] : lane == 5 ? yc[5] : lane == 6 ? yc[6] : yc[7];
        INP[(size_t)lane * N_LAST + i] = fmaxf((v - muc) * rc * ggc + bvc, 0.f);
    }
}

// scalar head: y[b] = X[b,i,:FIN]@w, BN over batch, relu -> Z (B, n_nodes)
template<int FIN>
__global__ void k_head_scalar(const float* __restrict__ X, const float* __restrict__ w,
                              const float* __restrict__ g, const float* __restrict__ bb,
                              float* __restrict__ Z, int n_nodes, long xbs, int xoff) {
    int i = blockIdx.x * 256 + threadIdx.x;
    if (i >= n_nodes) return;
    float y[BB];
    float s1 = 0.f, s2 = 0.f;
    const float4* wr = (const float4*)w;
    for (int b = 0; b < BB; b++) {
        const float4* xr = (const float4*)(X + (size_t)b * xbs + (size_t)(i + xoff) * FIN);
        float acc = 0.f;
#pragma unroll
        for (int q = 0; q < FIN / 4; q++) {
            float4 x = xr[q], u = wr[q];
            acc += x.x * u.x + x.y * u.y + x.z * u.z + x.w * u.w;
        }
        y[b] = acc; s1 += acc; s2 += acc * acc;
    }
    float mu = s1 / BB, var = s2 / BB - mu * mu;
    float rs = rsqrtf(var + EPSF);
    float gg = g[i], bv = bb[i];
    for (int b = 0; b < BB; b++)
        Z[(size_t)b * n_nodes + i] = fmaxf((y[b] - mu) * rs * gg + bv, 0.f);
}

// latent layer 1 fused
__global__ void k_lat1(const float* __restrict__ INP, const float* __restrict__ W,
                       const float* __restrict__ g, const float* __restrict__ bb,
                       float* __restrict__ H1R) {
    int j = blockIdx.x;
    int w = threadIdx.x >> 6;
    int lane = threadIdx.x & 63;
    const float* xr = INP + (size_t)w * N_LAST;
    const float* wr = W + (size_t)j * N_LAST;
    float s = 0.f;
    for (int k = lane; k < N_LAST; k += 64) s += xr[k] * wr[k];
    for (int o = 32; o > 0; o >>= 1) s += __shfl_down(s, o);
    __shared__ float sh[BB];
    if (lane == 0) sh[w] = s;
    __syncthreads();
    if (threadIdx.x < BB) {
        float s1 = 0.f, s2 = 0.f;
        for (int q = 0; q < BB; q++) { float y = sh[q]; s1 += y; s2 += y * y; }
        float mu = s1 / BB, var = s2 / BB - mu * mu;
        float rs = rsqrtf(var + EPSF);
        H1R[threadIdx.x * 32 + j] = fmaxf((sh[threadIdx.x] - mu) * rs * g[j] + bb[j], 0.f);
    }
}

// latent layer 2 fused
__global__ void k_lat2(const float* __restrict__ H1R, const float* __restrict__ W2,
                       const float* __restrict__ g, const float* __restrict__ bb,
                       float* __restrict__ out_lat) {
    int b = threadIdx.x >> 4, j = threadIdx.x & 15;
    float acc = 0.f;
    for (int k = 0; k < 32; k++) acc += H1R[b * 32 + k] * W2[j * 32 + k];
    __shared__ float sh[128];
    sh[threadIdx.x] = acc;
    __syncthreads();
    float s1 = 0.f, s2 = 0.f;
    for (int q = 0; q < BB; q++) { float y = sh[q * 16 + j]; s1 += y; s2 += y * y; }
    float mu = s1 / BB, var = s2 / BB - mu * mu;
    float rs = rsqrtf(var + EPSF);
    out_lat[b * 16 + j] = fmaxf((acc - mu) * rs * g[j] + bb[j], 0.f);
}

// ============================================================
extern "C" void kernel_launch(void* const* d_in, const int* in_sizes, int n_in,
                              void* d_out, int out_size, void* d_ws, size_t ws_size,
                              hipStream_t stream) {
    const float* data      = (const float*)d_in[0];
    const float* t         = (const float*)d_in[1];
    const float* t_D       = (const float*)d_in[2];
    const float* w_inc0    = (const float*)d_in[3];
    const float* w_inc1    = (const float*)d_in[4];
    const float* w_s0      = (const float*)d_in[5];
    const float* w_s1      = (const float*)d_in[6];
    const float* w_att_in0 = (const float*)d_in[7];
    const float* w_att_in1 = (const float*)d_in[8];
    const float* w_att_s0  = (const float*)d_in[9];
    const float* w_att_s1  = (const float*)d_in[10];
    const float* gb_g0     = (const float*)d_in[11];
    const float* gb_b0     = (const float*)d_in[12];
    const float* gb_g1     = (const float*)d_in[13];
    const float* gb_b1     = (const float*)d_in[14];
    const float* w_out0    = (const float*)d_in[15];
    const float* w_out1    = (const float*)d_in[16];
    const float* w_sout0   = (const float*)d_in[17];
    const float* w_sout1   = (const float*)d_in[18];
    const float* gbd_g0    = (const float*)d_in[19];
    const float* gbd_b0    = (const float*)d_in[20];
    const float* gbd_g1    = (const float*)d_in[21];
    const float* gbd_b1    = (const float*)d_in[22];
    const float* catt_w    = (const float*)d_in[23];
    const float* catt_bn_g = (const float*)d_in[24];
    const float* catt_bn_b = (const float*)d_in[25];
    const float* conc_w    = (const float*)d_in[26];
    const float* b_bn_g    = (const float*)d_in[27];
    const float* b_bn_b    = (const float*)d_in[28];
    const float* concd_w   = (const float*)d_in[29];
    const float* bd_bn_g   = (const float*)d_in[30];
    const float* bd_bn_b   = (const float*)d_in[31];
    const float* lat_w1    = (const float*)d_in[32];
    const float* lat_bn1_g = (const float*)d_in[33];
    const float* lat_bn1_b = (const float*)d_in[34];
    const float* lat_w2    = (const float*)d_in[35];
    const float* lat_bn2_g = (const float*)d_in[36];
    const float* lat_bn2_b = (const float*)d_in[37];
    const int* Ag_row   = (const int*)d_in[38];
    const int* Ag_col   = (const int*)d_in[39];
    const int* enc_src0 = (const int*)d_in[40];
    const int* enc_dst0 = (const int*)d_in[41];
    const int* enc_src1 = (const int*)d_in[42];
    const int* enc_dst1 = (const int*)d_in[43];
    const int* dec_src0 = (const int*)d_in[44];
    const int* dec_dst0 = (const int*)d_in[45];
    const int* dec_src1 = (const int*)d_in[46];
    const int* dec_dst1 = (const int*)d_in[47];

    const int nnz = in_sizes[2];
    const int E0  = in_sizes[40];
    const int E1  = in_sizes[42];
    const int ED0 = in_sizes[44];
    const int ED1 = in_sizes[46];
    int EDMAX = (ED0 > ED1 ? ED0 : ED1);
    if (nnz > EDMAX) EDMAX = nnz;

    // ---- workspace arena ----
    char* wsb = (char*)d_ws;
    size_t off = 0;
    auto alloc = [&](size_t bytes) -> void* {
        void* p = wsb + off;
        off += (bytes + 255) & ~(size_t)255;
        return p;
    };
    const size_t ARENA = (size_t)BB * N_GO * FF;
    float* P0 = (float*)alloc(ARENA * 4);
    float* P1 = (float*)alloc(ARENA * 4);
    float* P2 = (float*)alloc(ARENA * 4);
    float* P3 = (float*)alloc(ARENA * 4);
    float* EDGEV = (float*)alloc((size_t)BB * E0 * 4);
    float* ASRC = (float*)alloc((size_t)BB * N_GO * 4);
    float* ADST = (float*)alloc((size_t)BB * N_GO * 4);
    float* VS   = (float*)alloc((size_t)BB * N_GO * 4);
    float* SUMS = (float*)alloc(2 * BB * FF * 4);
    float* INP  = (float*)alloc((size_t)BB * N_LAST * 4);
    float* OUTD = (float*)alloc((size_t)BB * N_GO * 4);
    float* H1R  = (float*)alloc(BB * 32 * 4);
    float* DATAT = (float*)alloc((size_t)N_GENES * BB * 4);
    int* RS   = (int*)alloc(N_GO * 4);
    int* RE   = (int*)alloc(N_GO * 4);
    int* DEGI = (int*)alloc(N_GENES * 4);
    int* RSD  = (int*)alloc((N_GENES + 1) * 4);
    int* CURS = (int*)alloc(N_GENES * 4);
    int* CSRD = (int*)alloc((size_t)EDMAX * 4);      // dec CSR dst / gene CSR row
    float* CSRT = (float*)alloc((size_t)nnz * 4);    // gene CSR tD

    float* out_lat = (float*)d_out;                 // (B,16)
    float* out_xd  = out_lat + BB * L_DIM;          // (B,20000)
    float* out_att = out_xd + (size_t)BB * N_GENES; // (B,4000,5)

    dim3 blk(256);
    auto g1 = [](long n) { return dim3((unsigned)((n + 255) / 256)); };
    auto g2 = [](long n, int y) { return dim3((unsigned)((n + 255) / 256), (unsigned)y); };
    auto gw = [](int n) { return dim3((unsigned)((n + 3) / 4)); };  // wave-per-row
    const int LNB = 1024;
    const int LWAVES = LNB * 4;
    const int ANB = 256;                  // per-batch blocks for XCD-pinned agg
    const int N1 = N_GO - P0_; // 8000

    // ---- stage 0: gene -> GO ----
    k_tr_data<<<g1(N_GENES * BB), blk, 0, stream>>>(data, DATAT);
    k_bounds_bs<<<g1(N_GO), blk, 0, stream>>>(Ag_row, RS, RE, nnz, N_GO);
    k_gene2go_w<<<gw(N_GO), blk, 0, stream>>>(DATAT, t, Ag_col, RS, RE, P0, nnz);

    // ---- encoder 0 (n=12000) ----
    k_linear2_att8<true><<<dim3(LNB), blk, 0, stream>>>(P0, w_inc0, w_s0, w_att_in0, w_att_s0,
        P1, P2, ASRC, ADST, VS, N_GO, (long)N_GO * IN_F, 0, LWAVES);
    k_bounds_bs<<<g1(N_GO), blk, 0, stream>>>(enc_src0, RS, RE, E0, N_GO);
    k_edge_v<<<g2(E0, BB), blk, 0, stream>>>(ASRC, ADST, enc_src0, enc_dst0, EDGEV, E0, N_GO);
    hipMemsetAsync(SUMS, 0, 2 * BB * FF * 4, stream);
    k_agg_enc_f<<<dim3(ANB * 8), blk, 0, stream>>>(P1, P2, EDGEV, VS, enc_dst0, RS, RE, P3, SUMS, N_GO, E0, ANB);
    k_ln_apply_relu<<<g2((long)N_GO * FF, BB), blk, 0, stream>>>(P3, SUMS, gb_g0, gb_b0, P0, N_GO, FF);

    // ---- encoder 1 (n=8000, x = P0[:,4000:,:]) ----
    k_lin64d<true><<<dim3(LNB), blk, 0, stream>>>(P0, w_inc1, w_s1, w_att_in1, w_att_s1,
        P1, P2, ASRC, ADST, VS, N1, (long)N_GO * FF, P0_, LWAVES);
    k_bounds_bs<<<g1(N1), blk, 0, stream>>>(enc_src1, RS, RE, E1, N1);
    k_edge_v<<<g2(E1, BB), blk, 0, stream>>>(ASRC, ADST, enc_src1, enc_dst1, EDGEV, E1, N1);
    hipMemsetAsync(SUMS, 0, 2 * BB * FF * 4, stream);
    k_agg_enc_f<<<dim3(ANB * 8), blk, 0, stream>>>(P1, P2, EDGEV, VS, enc_dst1, RS, RE, P3, SUMS, N1, E1, ANB);
    k_ln_apply_relu<<<g2((long)N1 * FF, BB), blk, 0, stream>>>(P3, SUMS, gb_g1, gb_b1, P0, N1, FF);

    // ---- heads (x = P0[:,4000:,:] of (B,8000,64)) ----
    k_heads<<<gw(N_LAST), blk, 0, stream>>>(P0, catt_w, conc_w, catt_bn_g, catt_bn_b,
                                            b_bn_g, b_bn_b, out_att, INP, (long)N1 * FF, P0_);

    // ---- decoder 0 (in n=4000 -> rows 8000), CSR gather ----
    k_lin64d<false><<<dim3(LNB), blk, 0, stream>>>(P0, w_out0, w_sout0, nullptr, nullptr,
        P1, P2, nullptr, nullptr, nullptr, N_LAST, (long)N1 * FF, P0_, LWAVES);
    hipMemsetAsync(DEGI, 0, 8000 * 4, stream);
    k_deg_i<<<g1(ED0), blk, 0, stream>>>(dec_src0, DEGI, ED0);
    k_scan<<<dim3(1), dim3(1024), 0, stream>>>(DEGI, RSD, CURS, 8000);
    k_scatter<<<g1(ED0), blk, 0, stream>>>(dec_src0, dec_dst0, CURS, CSRD, ED0);
    hipMemsetAsync(SUMS, 0, 2 * BB * FF * 4, stream);
    k_agg_dec64<<<dim3(ANB * 8), blk, 0, stream>>>(P1, P2, RSD, CSRD, P3, SUMS, 8000, N_LAST, 4000, ANB);
    k_ln_apply_relu<<<g2((long)8000 * FF, BB), blk, 0, stream>>>(P3, SUMS, gbd_g0, gbd_b0, P0, 8000, FF);

    // ---- decoder 1 (in n=8000 F=64 -> rows 12000 F=8), CSR gather ----
    k_lin8d<<<dim3(LNB), blk, 0, stream>>>(P0, w_out1, w_sout1, P1, P2, 8000, (long)8000 * FF, 0, LWAVES);
    hipMemsetAsync(DEGI, 0, N_GO * 4, stream);
    k_deg_i<<<g1(ED1), blk, 0, stream>>>(dec_src1, DEGI, ED1);
    k_scan<<<dim3(1), dim3(1024), 0, stream>>>(DEGI, RSD, CURS, N_GO);
    k_scatter<<<g1(ED1), blk, 0, stream>>>(dec_src1, dec_dst1, CURS, CSRD, ED1);
    k_agg_dec8<<<gw(N_GO), blk, 0, stream>>>(P1, P2, RSD, CSRD, P3, N_GO, 8000, 4000);
    hipMemsetAsync(SUMS, 0, 2 * BB * IN_F * 4, stream);
    k_ln_stats<<<dim3((N_GO + 511) / 512, BB), blk, 0, stream>>>(P3, SUMS, N_GO, IN_F, 512);
    k_ln_apply_relu<<<g2((long)N_GO * IN_F, BB), blk, 0, stream>>>(P3, SUMS, gbd_g1, gbd_b1, P0, N_GO, IN_F);

    // ---- out_D head + x_D gather (column-CSR of Ag) ----
    k_head_scalar<IN_F><<<g1(N_GO), blk, 0, stream>>>(P0, concd_w, bd_bn_g, bd_bn_b, OUTD, N_GO, (long)N_GO * IN_F, 0);
    hipMemsetAsync(DEGI, 0, N_GENES * 4, stream);
    k_deg_i<<<g1(nnz), blk, 0, stream>>>(Ag_col, DEGI, nnz);
    k_scan<<<dim3(1), dim3(1024), 0, stream>>>(DEGI, RSD, CURS, N_GENES);
    k_scatter2<<<g1(nnz), blk, 0, stream>>>(Ag_col, Ag_row, t_D, CURS, CSRD, CSRT, nnz);
    k_xd_g<<<gw(N_GENES), blk, 0, stream>>>(OUTD, RSD, CSRD, CSRT, out_xd);

    // ---- latent MLP (fused) ----
    k_lat1<<<dim3(32), dim3(512), 0, stream>>>(INP, lat_w1, lat_bn1_g, lat_bn1_b, H1R);
    k_lat2<<<dim3(1), dim3(128), 0, stream>>>(H1R, lat_w2, lat_bn2_g, lat_bn2_b, out_lat);

    (void)n_in; (void)out_size; (void)ws_size;
}

// Round 20
// 511.348 us; speedup vs baseline: 1.0191x; 1.0191x over previous
//
#include <hip/hip_runtime.h>
#include <math.h>

// ---- problem constants (match reference) ----
#define BB 8
#define N_GO 12000
#define N_GENES 20000
#define IN_F 8
#define FF 64
#define D_ATT 5
#define L_DIM 16
#define N_LAST 4000
#define P0_ 4000
#define EPSF 1e-5f

// ============================================================
// row bounds via binary search on sorted src: rs[r]=lb(r), re[r]=lb(r+1)
__global__ void k_bounds_bs(const int* __restrict__ src, int* __restrict__ rs,
                            int* __restrict__ re, int E, int n) {
    int r = blockIdx.x * 256 + threadIdx.x;
    if (r >= n) return;
    int lo = 0, hi = E;
    while (lo < hi) { int m = (lo + hi) >> 1; if (src[m] < r) lo = m + 1; else hi = m; }
    rs[r] = lo;
    int lo2 = lo, hi2 = E;
    while (lo2 < hi2) { int m = (lo2 + hi2) >> 1; if (src[m] < r + 1) lo2 = m + 1; else hi2 = m; }
    re[r] = lo2;
}

// data (B, N_GENES) -> dataT (N_GENES, B)
__global__ void k_tr_data(const float* __restrict__ data, float* __restrict__ dataT) {
    int idx = blockIdx.x * 256 + threadIdx.x;
    if (idx >= N_GENES * BB) return;
    int g = idx >> 3, b = idx & 7;
    dataT[idx] = data[b * N_GENES + g];
}

// wave per GO row: lanes = 8 edge-slots x 8 features; dataT broadcast loads
__global__ void k_gene2go_w(const float* __restrict__ dataT, const float* __restrict__ t,
                            const int* __restrict__ col, const int* __restrict__ rs,
                            const int* __restrict__ re, float* __restrict__ x0, int nnz) {
    int wid = blockIdx.x * 4 + (threadIdx.x >> 6);
    if (wid >= N_GO) return;
    int lane = threadIdx.x & 63;
    int f = lane & 7, eo = lane >> 3;
    int e0 = rs[wid], e1 = re[wid];
    float acc[BB];
#pragma unroll
    for (int b = 0; b < BB; b++) acc[b] = 0.f;
    for (int e = e0; e < e1; e += 8) {
        int ee = e + eo;
        bool ok = ee < e1;
        int ec = ok ? ee : (e1 - 1);
        int c = col[ec];
        float tv = ok ? t[(size_t)f * nnz + ee] : 0.f;
        const float4* dt = (const float4*)(dataT + (size_t)c * 8);
        float4 d0 = dt[0], d1 = dt[1];
        acc[0] += tv * d0.x; acc[1] += tv * d0.y; acc[2] += tv * d0.z; acc[3] += tv * d0.w;
        acc[4] += tv * d1.x; acc[5] += tv * d1.y; acc[6] += tv * d1.z; acc[7] += tv * d1.w;
    }
#pragma unroll
    for (int b = 0; b < BB; b++) {
        acc[b] += __shfl_xor(acc[b], 8);
        acc[b] += __shfl_xor(acc[b], 16);
        acc[b] += __shfl_xor(acc[b], 32);
    }
    if (lane < IN_F) {
#pragma unroll
        for (int b = 0; b < BB; b++)
            x0[((size_t)b * N_GO + wid) * IN_F + lane] = acc[b];
    }
}

// dual linear FIN=8 (enc0): weights tiny, both matrices in regs (pinned)
template<bool SCAL>
__global__ __launch_bounds__(256, 2)
void k_linear2_att8(const float* __restrict__ X, const float* __restrict__ W1,
                    const float* __restrict__ W2, const float* __restrict__ watt,
                    const float* __restrict__ ws, float* __restrict__ Y1,
                    float* __restrict__ Y2, float* __restrict__ ASRC,
                    float* __restrict__ ADST, float* __restrict__ VS,
                    int n_nodes, long xbs, int xoff, int total_waves) {
    __shared__ float w1s[IN_F * 65];
    __shared__ float w2s[IN_F * 65];
    int lane = threadIdx.x & 63;
    for (int i = threadIdx.x; i < IN_F * FF; i += 256) {
        int fo = i >> 3, k = i & 7;          // W row-major [fo][k]
        w1s[k * 65 + fo] = W1[i];
        w2s[k * 65 + fo] = W2[i];
    }
    __syncthreads();
    float w1r[IN_F], w2r[IN_F];
#pragma unroll
    for (int k = 0; k < IN_F; k++) {
        w1r[k] = w1s[k * 65 + lane];
        w2r[k] = w2s[k * 65 + lane];
        asm volatile("" : "+v"(w1r[k]));
        asm volatile("" : "+v"(w2r[k]));
    }
    float wa = 0.f, wb = 0.f, wc = 0.f;
    if (SCAL) { wa = watt[lane]; wb = watt[FF + lane]; wc = ws[lane]; }
    int wid = blockIdx.x * 4 + (threadIdx.x >> 6);
    for (int n = wid; n < n_nodes; n += total_waves) {
        for (int b = 0; b < BB; b++) {
            const float* xr = X + (size_t)b * xbs + (size_t)(n + xoff) * IN_F;
            float4 x0 = *(const float4*)xr, x1 = *(const float4*)(xr + 4);
            float a1 = x0.x * w1r[0] + x0.y * w1r[1] + x0.z * w1r[2] + x0.w * w1r[3]
                     + x1.x * w1r[4] + x1.y * w1r[5] + x1.z * w1r[6] + x1.w * w1r[7];
            float a2 = x0.x * w2r[0] + x0.y * w2r[1] + x0.z * w2r[2] + x0.w * w2r[3]
                     + x1.x * w2r[4] + x1.y * w2r[5] + x1.z * w2r[6] + x1.w * w2r[7];
            Y1[((size_t)b * n_nodes + n) * FF + lane] = a1;
            Y2[((size_t)b * n_nodes + n) * FF + lane] = a2;
            if (SCAL) {
                float s0 = a1 * wa, s1 = a1 * wb, s2 = a2 * wc;
                for (int m = 1; m < 64; m <<= 1) {
                    s0 += __shfl_xor(s0, m);
                    s1 += __shfl_xor(s1, m);
                    s2 += __shfl_xor(s2, m);
                }
                if (lane == 0) {
                    ASRC[b * n_nodes + n] = s0;
                    ADST[b * n_nodes + n] = s1;
                    VS[b * n_nodes + n] = 1.f / (1.f + expf(-s2));
                }
            }
        }
    }
}

// dual linear FIN=64 FOUT=64, weights register-PINNED (asm) to defeat remat.
template<bool SCAL>
__global__ __launch_bounds__(256, 1)
void k_lin64d(const float* __restrict__ X, const float* __restrict__ W1,
              const float* __restrict__ W2, const float* __restrict__ watt,
              const float* __restrict__ ws, float* __restrict__ Y1,
              float* __restrict__ Y2, float* __restrict__ ASRC,
              float* __restrict__ ADST, float* __restrict__ VS,
              int n_nodes, long xbs, int xoff, int total_waves) {
    __shared__ float w1s[FF * 65];
    __shared__ float w2s[FF * 65];
    int lane = threadIdx.x & 63;
    for (int i = threadIdx.x; i < FF * FF; i += 256) {
        int fo = i >> 6, k = i & 63;
        w1s[fo * 65 + k] = W1[i];
        w2s[fo * 65 + k] = W2[i];
    }
    __syncthreads();
    float w1r[FF], w2r[FF];
#pragma unroll
    for (int k = 0; k < FF; k++) {
        w1r[k] = w1s[lane * 65 + k];
        w2r[k] = w2s[lane * 65 + k];
        asm volatile("" : "+v"(w1r[k]));
        asm volatile("" : "+v"(w2r[k]));
    }
    float wa = 0.f, wb = 0.f, wc = 0.f;
    if (SCAL) { wa = watt[lane]; wb = watt[FF + lane]; wc = ws[lane]; }
    int wid = blockIdx.x * 4 + (threadIdx.x >> 6);
    for (int n = wid; n < n_nodes; n += total_waves) {
        for (int b = 0; b < BB; b++) {
            const float* xr = X + (size_t)b * xbs + (size_t)(n + xoff) * FF;
            float a1 = 0.f, a2 = 0.f;
#pragma unroll
            for (int k = 0; k < FF; k += 4) {
                float4 x = *(const float4*)(xr + k);
                a1 += x.x * w1r[k] + x.y * w1r[k + 1] + x.z * w1r[k + 2] + x.w * w1r[k + 3];
                a2 += x.x * w2r[k] + x.y * w2r[k + 1] + x.z * w2r[k + 2] + x.w * w2r[k + 3];
            }
            Y1[((size_t)b * n_nodes + n) * FF + lane] = a1;
            Y2[((size_t)b * n_nodes + n) * FF + lane] = a2;
            if (SCAL) {
                float s0 = a1 * wa, s1 = a1 * wb, s2 = a2 * wc;
                for (int m = 1; m < 64; m <<= 1) {
                    s0 += __shfl_xor(s0, m);
                    s1 += __shfl_xor(s1, m);
                    s2 += __shfl_xor(s2, m);
                }
                if (lane == 0) {
                    ASRC[b * n_nodes + n] = s0;
                    ADST[b * n_nodes + n] = s1;
                    VS[b * n_nodes + n] = 1.f / (1.f + expf(-s2));
                }
            }
        }
    }
}

// dual linear FIN=64 FOUT=8 (dec1): weights pinned, 8 node-slots/wave
__global__ __launch_bounds__(256, 1)
void k_lin8d(const float* __restrict__ X, const float* __restrict__ W1,
             const float* __restrict__ W2, float* __restrict__ Y1,
             float* __restrict__ Y2, int n_nodes, long xbs, int xoff,
             int total_waves) {
    __shared__ float w1s[IN_F * 65];
    __shared__ float w2s[IN_F * 65];
    int lane = threadIdx.x & 63;
    for (int i = threadIdx.x; i < IN_F * FF; i += 256) {
        int fo = i >> 6, k = i & 63;
        w1s[fo * 65 + k] = W1[i];
        w2s[fo * 65 + k] = W2[i];
    }
    __syncthreads();
    int of = lane & 7;
    int slot = lane >> 3;
    float w1r[FF], w2r[FF];
#pragma unroll
    for (int k = 0; k < FF; k++) {
        w1r[k] = w1s[of * 65 + k];
        w2r[k] = w2s[of * 65 + k];
        asm volatile("" : "+v"(w1r[k]));
        asm volatile("" : "+v"(w2r[k]));
    }
    int wid = blockIdx.x * 4 + (threadIdx.x >> 6);
    for (long n0 = (long)wid * 8; n0 < n_nodes; n0 += (long)total_waves * 8) {
        int n = (int)n0 + slot;
        bool ok = (n < n_nodes);
        int nn = ok ? n : (n_nodes - 1);
        for (int b = 0; b < BB; b++) {
            const float* xr = X + (size_t)b * xbs + (size_t)(nn + xoff) * FF;
            float a1 = 0.f, a2 = 0.f;
#pragma unroll
            for (int k = 0; k < FF; k += 4) {
                float4 x = *(const float4*)(xr + k);
                a1 += x.x * w1r[k] + x.y * w1r[k + 1] + x.z * w1r[k + 2] + x.w * w1r[k + 3];
                a2 += x.x * w2r[k] + x.y * w2r[k + 1] + x.z * w2r[k + 2] + x.w * w2r[k + 3];
            }
            if (ok) {
                Y1[((size_t)b * n_nodes + n) * IN_F + of] = a1;
                Y2[((size_t)b * n_nodes + n) * IN_F + of] = a2;
            }
        }
    }
}

// v[b,e] = exp(tanh(a_src[b,src[e]] + a_dst[b,dst[e]]))  (fully parallel)
__global__ void k_edge_v(const float* __restrict__ a_src, const float* __restrict__ a_dst,
                         const int* __restrict__ src, const int* __restrict__ dst,
                         float* __restrict__ v, int E, int n_nodes) {
    int e = blockIdx.x * 256 + threadIdx.x;
    if (e >= E) return;
    int b = blockIdx.y;
    v[(size_t)b * E + e] = expf(tanhf(a_src[b * n_nodes + src[e]] + a_dst[b * n_nodes + dst[e]]));
}

// fused encoder aggregation: XCD-pinned batch, wave per row, x4-unrolled gather,
// precomputed edge weights, LN stats fused.  (R13-proven form)
__global__ void k_agg_enc_f(const float* __restrict__ Xin, const float* __restrict__ Xs,
                            const float* __restrict__ EDGEV, const float* __restrict__ VS,
                            const int* __restrict__ dst, const int* __restrict__ rs,
                            const int* __restrict__ re, float* __restrict__ Out,
                            float* __restrict__ sums, int n_nodes, int E, int nblk) {
    int b = blockIdx.x & 7;
    int wid = threadIdx.x >> 6;
    int lane = threadIdx.x & 63;
    const float* Xb  = Xin + (size_t)b * n_nodes * FF;
    const float* Xsb = Xs  + (size_t)b * n_nodes * FF;
    const float* vv  = EDGEV + (size_t)b * E;
    float s1 = 0.f, s2 = 0.f;
    for (int r = (blockIdx.x >> 3) * 4 + wid; r < n_nodes; r += nblk * 4) {
        int e0 = rs[r], e1 = re[r];
        float sv0 = 0.f, sv1 = 0.f, sv2 = 0.f, sv3 = 0.f;
        float acc0 = 0.f, acc1 = 0.f, acc2 = 0.f, acc3 = 0.f;
        int e = e0;
        for (; e + 3 < e1; e += 4) {
            int d0 = dst[e], d1 = dst[e + 1], d2 = dst[e + 2], d3 = dst[e + 3];
            float v0 = vv[e], v1 = vv[e + 1], v2 = vv[e + 2], v3 = vv[e + 3];
            sv0 += v0; sv1 += v1; sv2 += v2; sv3 += v3;
            acc0 += v0 * Xb[(size_t)d0 * FF + lane];
            acc1 += v1 * Xb[(size_t)d1 * FF + lane];
            acc2 += v2 * Xb[(size_t)d2 * FF + lane];
            acc3 += v3 * Xb[(size_t)d3 * FF + lane];
        }
        for (; e < e1; e++) {
            int d0 = dst[e];
            float v0 = vv[e];
            sv0 += v0;
            acc0 += v0 * Xb[(size_t)d0 * FF + lane];
        }
        float sv = (sv0 + sv1) + (sv2 + sv3);
        float acc = (acc0 + acc1) + (acc2 + acc3);
        float o = (e1 > e0) ? acc / sv : 0.f;
        o += Xsb[(size_t)r * FF + lane] * VS[b * n_nodes + r];
        Out[((size_t)b * n_nodes + r) * FF + lane] = o;
        s1 += o; s2 += o * o;
    }
    __shared__ float sh1[4][64], sh2[4][64];
    sh1[wid][lane] = s1; sh2[wid][lane] = s2;
    __syncthreads();
    if (wid == 0) {
        float a = sh1[0][lane] + sh1[1][lane] + sh1[2][lane] + sh1[3][lane];
        float c = sh2[0][lane] + sh2[1][lane] + sh2[2][lane] + sh2[3][lane];
        atomicAdd(&sums[(b * FF + lane) * 2],     a);
        atomicAdd(&sums[(b * FF + lane) * 2 + 1], c);
    }
}

// LN over node axis: accumulate sum & sumsq per (b,f)  (used for Fdim=8 only)
__global__ void k_ln_stats(const float* __restrict__ X, float* __restrict__ sums,
                           int n_nodes, int Fdim, int npb) {
    int b = blockIdx.y;
    int f = threadIdx.x & (Fdim - 1);
    int nl = threadIdx.x / Fdim;
    int stride = 256 / Fdim;
    int n0 = blockIdx.x * npb;
    int n1 = n0 + npb; if (n1 > n_nodes) n1 = n_nodes;
    const float* xb = X + (size_t)b * n_nodes * Fdim;
    float s1 = 0.f, s2 = 0.f;
    for (int n = n0 + nl; n < n1; n += stride) {
        float x = xb[(size_t)n * Fdim + f];
        s1 += x; s2 += x * x;
    }
    __shared__ float sh1[256], sh2[256];
    sh1[threadIdx.x] = s1; sh2[threadIdx.x] = s2;
    __syncthreads();
    for (int o = 128; o >= Fdim; o >>= 1) {
        if (threadIdx.x < o) { sh1[threadIdx.x] += sh1[threadIdx.x + o]; sh2[threadIdx.x] += sh2[threadIdx.x + o]; }
        __syncthreads();
    }
    if (threadIdx.x < Fdim) {
        atomicAdd(&sums[(b * Fdim + threadIdx.x) * 2],     sh1[threadIdx.x]);
        atomicAdd(&sums[(b * Fdim + threadIdx.x) * 2 + 1], sh2[threadIdx.x]);
    }
}

// Y = relu((X - mu)*rsqrt(var+eps)*g[n] + bb[n])
__global__ void k_ln_apply_relu(const float* __restrict__ X, const float* __restrict__ sums,
                                const float* __restrict__ g, const float* __restrict__ bb,
                                float* __restrict__ Y, int n_nodes, int Fdim) {
    long idx = (long)blockIdx.x * 256 + threadIdx.x;
    if (idx >= (long)n_nodes * Fdim) return;
    int b = blockIdx.y;
    int n = (int)(idx / Fdim);
    int f = (int)(idx % Fdim);
    float s1 = sums[(b * Fdim + f) * 2], s2 = sums[(b * Fdim + f) * 2 + 1];
    float mu = s1 / n_nodes;
    float var = s2 / n_nodes - mu * mu;
    float rs = rsqrtf(var + EPSF);
    size_t o = (size_t)b * n_nodes * Fdim + idx;
    float y = (X[o] - mu) * rs * g[n] + bb[n];
    Y[o] = fmaxf(y, 0.f);
}

// int degree histogram
__global__ void k_deg_i(const int* __restrict__ src, int* __restrict__ deg, int E) {
    int e = blockIdx.x * 256 + threadIdx.x;
    if (e < E) atomicAdd(&deg[src[e]], 1);
}

// single-block exclusive scan: rsd[0..n] prefix, cursor copy
__global__ void k_scan(const int* __restrict__ deg, int* __restrict__ rsd,
                       int* __restrict__ cursor, int n) {
    __shared__ int part[1024];
    int t = threadIdx.x;
    int chunk = (n + 1023) >> 10;
    int s0 = t * chunk, s1 = s0 + chunk; if (s1 > n) s1 = n;
    int s = 0;
    for (int i = s0; i < s1 && i < n; i++) s += deg[i];
    part[t] = s;
    __syncthreads();
    for (int o = 1; o < 1024; o <<= 1) {
        int v = (t >= o) ? part[t - o] : 0;
        __syncthreads();
        part[t] += v;
        __syncthreads();
    }
    int base = (t == 0) ? 0 : part[t - 1];
    for (int i = s0; i < s1 && i < n; i++) {
        rsd[i] = base; cursor[i] = base;
        base += deg[i];
    }
    if (t == 1023) rsd[n] = part[1023];
}

// scatter dst into CSR order
__global__ void k_scatter(const int* __restrict__ src, const int* __restrict__ dst,
                          int* __restrict__ cursor, int* __restrict__ csrd, int E) {
    int e = blockIdx.x * 256 + threadIdx.x;
    if (e >= E) return;
    int pos = atomicAdd(&cursor[src[e]], 1);
    csrd[pos] = dst[e];
}

// scatter (row, tD) into column-CSR order
__global__ void k_scatter2(const int* __restrict__ key, const int* __restrict__ row,
                           const float* __restrict__ tD, int* __restrict__ cursor,
                           int* __restrict__ csrr, float* __restrict__ csrt, int E) {
    int e = blockIdx.x * 256 + threadIdx.x;
    if (e >= E) return;
    int pos = atomicAdd(&cursor[key[e]], 1);
    csrr[pos] = row[e];
    csrt[pos] = tD[e];
}

// x_D gather: wave per gene, lane = (slot<<3)|batch; reduce over 8 slots
__global__ void k_xd_g(const float* __restrict__ outD, const int* __restrict__ rsg,
                       const int* __restrict__ csrr, const float* __restrict__ csrt,
                       float* __restrict__ xD) {
    int g = blockIdx.x * 4 + (threadIdx.x >> 6);
    if (g >= N_GENES) return;
    int lane = threadIdx.x & 63;
    int b = lane & 7, slot = lane >> 3;
    int e0 = rsg[g], e1 = rsg[g + 1];
    float acc = 0.f;
    for (int e = e0 + slot; e < e1; e += 8)
        acc += csrt[e] * outD[(size_t)b * N_GO + csrr[e]];
    acc += __shfl_xor(acc, 8);
    acc += __shfl_xor(acc, 16);
    acc += __shfl_xor(acc, 32);
    if (lane < BB)
        xD[(size_t)b * N_GENES + g] = acc;
}

// decoder aggregation F=64: XCD-pinned batch, CSR gather x4-unrolled, LN fused
__global__ void k_agg_dec64(const float* __restrict__ Xout, const float* __restrict__ Xs,
                            const int* __restrict__ rsd, const int* __restrict__ csrd,
                            float* __restrict__ Out, float* __restrict__ sums,
                            int n_rows, int n_in, int offset, int nblk) {
    int b = blockIdx.x & 7;
    int wid = threadIdx.x >> 6;
    int lane = threadIdx.x & 63;
    const float* Xb = Xout + (size_t)b * n_in * FF;
    int nxs = n_rows - offset;
    const float* Xsb = Xs + (size_t)b * nxs * FF;
    float s1 = 0.f, s2 = 0.f;
    for (int r = (blockIdx.x >> 3) * 4 + wid; r < n_rows; r += nblk * 4) {
        int e0 = rsd[r], e1 = rsd[r + 1];
        float acc0 = 0.f, acc1 = 0.f, acc2 = 0.f, acc3 = 0.f;
        int e = e0;
        for (; e + 3 < e1; e += 4) {
            acc0 += Xb[(size_t)csrd[e] * FF + lane];
            acc1 += Xb[(size_t)csrd[e + 1] * FF + lane];
            acc2 += Xb[(size_t)csrd[e + 2] * FF + lane];
            acc3 += Xb[(size_t)csrd[e + 3] * FF + lane];
        }
        for (; e < e1; e++) acc0 += Xb[(size_t)csrd[e] * FF + lane];
        float acc = (acc0 + acc1) + (acc2 + acc3);
        float o = (e1 > e0) ? acc / (float)(e1 - e0) : 0.f;
        if (r >= offset)
            o += Xsb[(size_t)(r - offset) * FF + lane];
        Out[((size_t)b * n_rows + r) * FF + lane] = o;
        s1 += o; s2 += o * o;
    }
    __shared__ float sh1[4][64], sh2[4][64];
    sh1[wid][lane] = s1; sh2[wid][lane] = s2;
    __syncthreads();
    if (wid == 0) {
        float a = sh1[0][lane] + sh1[1][lane] + sh1[2][lane] + sh1[3][lane];
        float c = sh2[0][lane] + sh2[1][lane] + sh2[2][lane] + sh2[3][lane];
        atomicAdd(&sums[(b * FF + lane) * 2],     a);
        atomicAdd(&sums[(b * FF + lane) * 2 + 1], c);
    }
}

// decoder aggregation F=8: 8 edge-slots x 8 features per wave
__global__ void k_agg_dec8(const float* __restrict__ Xout, const float* __restrict__ Xs,
                           const int* __restrict__ rsd, const int* __restrict__ csrd,
                           float* __restrict__ Out, int n_rows, int n_in, int offset) {
    int r = blockIdx.x * 4 + (threadIdx.x >> 6);
    if (r >= n_rows) return;
    int lane = threadIdx.x & 63;
    int f = lane & 7, slot = lane >> 3;
    int e0 = rsd[r], e1 = rsd[r + 1];
    float acc[BB];
#pragma unroll
    for (int b = 0; b < BB; b++) acc[b] = 0.f;
    for (int e = e0 + slot; e < e1; e += 8) {
        int d = csrd[e];
#pragma unroll
        for (int b = 0; b < BB; b++)
            acc[b] += Xout[((size_t)b * n_in + d) * IN_F + f];
    }
#pragma unroll
    for (int b = 0; b < BB; b++) {
        acc[b] += __shfl_xor(acc[b], 8);
        acc[b] += __shfl_xor(acc[b], 16);
        acc[b] += __shfl_xor(acc[b], 32);
    }
    float coef = (e1 > e0) ? 1.f / (float)(e1 - e0) : 0.f;
    int nxs = n_rows - offset;
    if (lane < IN_F) {
#pragma unroll
        for (int b = 0; b < BB; b++) {
            float o = acc[b] * coef;
            if (r >= offset)
                o += Xs[((size_t)b * nxs + (r - offset)) * IN_F + lane];
            Out[((size_t)b * n_rows + r) * IN_F + lane] = o;
        }
    }
}

// fused heads: wave per node. catt (5 outs, BN over b,d) + conc (1 out, BN over b)
__global__ void k_heads(const float* __restrict__ X, const float* __restrict__ Wa,
                        const float* __restrict__ wc, const float* __restrict__ ga,
                        const float* __restrict__ ba, const float* __restrict__ gc,
                        const float* __restrict__ bc, float* __restrict__ ATT,
                        float* __restrict__ INP, long xbs, int xoff) {
    int i = blockIdx.x * 4 + (threadIdx.x >> 6);
    if (i >= N_LAST) return;
    int lane = threadIdx.x & 63;
    float w0 = Wa[0 * FF + lane], w1 = Wa[1 * FF + lane], w2 = Wa[2 * FF + lane];
    float w3 = Wa[3 * FF + lane], w4 = Wa[4 * FF + lane];
    float wcv = wc[lane];
    float y[BB][D_ATT], yc[BB];
    float s1 = 0.f, s2 = 0.f;
#pragma unroll
    for (int b = 0; b < BB; b++) {
        float x = X[(size_t)b * xbs + (size_t)(i + xoff) * FF + lane];
        float p0 = x * w0, p1 = x * w1, p2 = x * w2, p3 = x * w3, p4 = x * w4, pc = x * wcv;
        for (int m = 1; m < 64; m <<= 1) {
            p0 += __shfl_xor(p0, m); p1 += __shfl_xor(p1, m); p2 += __shfl_xor(p2, m);
            p3 += __shfl_xor(p3, m); p4 += __shfl_xor(p4, m); pc += __shfl_xor(pc, m);
        }
        y[b][0] = p0; y[b][1] = p1; y[b][2] = p2; y[b][3] = p3; y[b][4] = p4;
        yc[b] = pc;
        s1 += p0 + p1 + p2 + p3 + p4;
        s2 += p0 * p0 + p1 * p1 + p2 * p2 + p3 * p3 + p4 * p4;
    }
    const float cnt = (float)(BB * D_ATT);
    float mu = s1 / cnt, var = s2 / cnt - mu * mu;
    float rsv = rsqrtf(var + EPSF);
    float gg = ga[i], bv = ba[i];
#pragma unroll
    for (int b = 0; b < BB; b++) {
        float yv = lane == 0 ? y[b][0] : lane == 1 ? y[b][1] : lane == 2 ? y[b][2]
                 : lane == 3 ? y[b][3] : y[b][4];
        if (lane < D_ATT)
            ATT[((size_t)b * N_LAST + i) * D_ATT + lane] = fmaxf((yv - mu) * rsv * gg + bv, 0.f);
    }
    float c1 = 0.f, c2 = 0.f;
#pragma unroll
    for (int b = 0; b < BB; b++) { c1 += yc[b]; c2 += yc[b] * yc[b]; }
    float muc = c1 / BB, varc = c2 / BB - muc * muc;
    float rc = rsqrtf(varc + EPSF);
    float ggc = gc[i], bvc = bc[i];
    if (lane < BB) {
        float v = lane == 0 ? yc[0] : lane == 1 ? yc[1] : lane == 2 ? yc[2] : lane == 3 ? yc[3]
                : lane == 4 ? yc[4] : lane == 5 ? yc[5] : lane == 6 ? yc[6] : yc[7];
        INP[(size_t)lane * N_LAST + i] = fmaxf((v - muc) * rc * ggc + bvc, 0.f);
    }
}

// scalar head: y[b] = X[b,i,:FIN]@w, BN over batch, relu -> Z (B, n_nodes)
template<int FIN>
__global__ void k_head_scalar(const float* __restrict__ X, const float* __restrict__ w,
                              const float* __restrict__ g, const float* __restrict__ bb,
                              float* __restrict__ Z, int n_nodes, long xbs, int xoff) {
    int i = blockIdx.x * 256 + threadIdx.x;
    if (i >= n_nodes) return;
    float y[BB];
    float s1 = 0.f, s2 = 0.f;
    const float4* wr = (const float4*)w;
    for (int b = 0; b < BB; b++) {
        const float4* xr = (const float4*)(X + (size_t)b * xbs + (size_t)(i + xoff) * FIN);
        float acc = 0.f;
#pragma unroll
        for (int q = 0; q < FIN / 4; q++) {
            float4 x = xr[q], u = wr[q];
            acc += x.x * u.x + x.y * u.y + x.z * u.z + x.w * u.w;
        }
        y[b] = acc; s1 += acc; s2 += acc * acc;
    }
    float mu = s1 / BB, var = s2 / BB - mu * mu;
    float rs = rsqrtf(var + EPSF);
    float gg = g[i], bv = bb[i];
    for (int b = 0; b < BB; b++)
        Z[(size_t)b * n_nodes + i] = fmaxf((y[b] - mu) * rs * gg + bv, 0.f);
}

// latent layer 1 fused
__global__ void k_lat1(const float* __restrict__ INP, const float* __restrict__ W,
                       const float* __restrict__ g, const float* __restrict__ bb,
                       float* __restrict__ H1R) {
    int j = blockIdx.x;
    int w = threadIdx.x >> 6;
    int lane = threadIdx.x & 63;
    const float* xr = INP + (size_t)w * N_LAST;
    const float* wr = W + (size_t)j * N_LAST;
    float s = 0.f;
    for (int k = lane; k < N_LAST; k += 64) s += xr[k] * wr[k];
    for (int o = 32; o > 0; o >>= 1) s += __shfl_down(s, o);
    __shared__ float sh[BB];
    if (lane == 0) sh[w] = s;
    __syncthreads();
    if (threadIdx.x < BB) {
        float s1 = 0.f, s2 = 0.f;
        for (int q = 0; q < BB; q++) { float y = sh[q]; s1 += y; s2 += y * y; }
        float mu = s1 / BB, var = s2 / BB - mu * mu;
        float rs = rsqrtf(var + EPSF);
        H1R[threadIdx.x * 32 + j] = fmaxf((sh[threadIdx.x] - mu) * rs * g[j] + bb[j], 0.f);
    }
}

// latent layer 2 fused
__global__ void k_lat2(const float* __restrict__ H1R, const float* __restrict__ W2,
                       const float* __restrict__ g, const float* __restrict__ bb,
                       float* __restrict__ out_lat) {
    int b = threadIdx.x >> 4, j = threadIdx.x & 15;
    float acc = 0.f;
    for (int k = 0; k < 32; k++) acc += H1R[b * 32 + k] * W2[j * 32 + k];
    __shared__ float sh[128];
    sh[threadIdx.x] = acc;
    __syncthreads();
    float s1 = 0.f, s2 = 0.f;
    for (int q = 0; q < BB; q++) { float y = sh[q * 16 + j]; s1 += y; s2 += y * y; }
    float mu = s1 / BB, var = s2 / BB - mu * mu;
    float rs = rsqrtf(var + EPSF);
    out_lat[b * 16 + j] = fmaxf((acc - mu) * rs * g[j] + bb[j], 0.f);
}

// ============================================================
extern "C" void kernel_launch(void* const* d_in, const int* in_sizes, int n_in,
                              void* d_out, int out_size, void* d_ws, size_t ws_size,
                              hipStream_t stream) {
    const float* data      = (const float*)d_in[0];
    const float* t         = (const float*)d_in[1];
    const float* t_D       = (const float*)d_in[2];
    const float* w_inc0    = (const float*)d_in[3];
    const float* w_inc1    = (const float*)d_in[4];
    const float* w_s0      = (const float*)d_in[5];
    const float* w_s1      = (const float*)d_in[6];
    const float* w_att_in0 = (const float*)d_in[7];
    const float* w_att_in1 = (const float*)d_in[8];
    const float* w_att_s0  = (const float*)d_in[9];
    const float* w_att_s1  = (const float*)d_in[10];
    const float* gb_g0     = (const float*)d_in[11];
    const float* gb_b0     = (const float*)d_in[12];
    const float* gb_g1     = (const float*)d_in[13];
    const float* gb_b1     = (const float*)d_in[14];
    const float* w_out0    = (const float*)d_in[15];
    const float* w_out1    = (const float*)d_in[16];
    const float* w_sout0   = (const float*)d_in[17];
    const float* w_sout1   = (const float*)d_in[18];
    const float* gbd_g0    = (const float*)d_in[19];
    const float* gbd_b0    = (const float*)d_in[20];
    const float* gbd_g1    = (const float*)d_in[21];
    const float* gbd_b1    = (const float*)d_in[22];
    const float* catt_w    = (const float*)d_in[23];
    const float* catt_bn_g = (const float*)d_in[24];
    const float* catt_bn_b = (const float*)d_in[25];
    const float* conc_w    = (const float*)d_in[26];
    const float* b_bn_g    = (const float*)d_in[27];
    const float* b_bn_b    = (const float*)d_in[28];
    const float* concd_w   = (const float*)d_in[29];
    const float* bd_bn_g   = (const float*)d_in[30];
    const float* bd_bn_b   = (const float*)d_in[31];
    const float* lat_w1    = (const float*)d_in[32];
    const float* lat_bn1_g = (const float*)d_in[33];
    const float* lat_bn1_b = (const float*)d_in[34];
    const float* lat_w2    = (const float*)d_in[35];
    const float* lat_bn2_g = (const float*)d_in[36];
    const float* lat_bn2_b = (const float*)d_in[37];
    const int* Ag_row   = (const int*)d_in[38];
    const int* Ag_col   = (const int*)d_in[39];
    const int* enc_src0 = (const int*)d_in[40];
    const int* enc_dst0 = (const int*)d_in[41];
    const int* enc_src1 = (const int*)d_in[42];
    const int* enc_dst1 = (const int*)d_in[43];
    const int* dec_src0 = (const int*)d_in[44];
    const int* dec_dst0 = (const int*)d_in[45];
    const int* dec_src1 = (const int*)d_in[46];
    const int* dec_dst1 = (const int*)d_in[47];

    const int nnz = in_sizes[2];
    const int E0  = in_sizes[40];
    const int E1  = in_sizes[42];
    const int ED0 = in_sizes[44];
    const int ED1 = in_sizes[46];
    int EDMAX = (ED0 > ED1 ? ED0 : ED1);
    if (nnz > EDMAX) EDMAX = nnz;

    // ---- workspace arena ----
    char* wsb = (char*)d_ws;
    size_t off = 0;
    auto alloc = [&](size_t bytes) -> void* {
        void* p = wsb + off;
        off += (bytes + 255) & ~(size_t)255;
        return p;
    };
    const size_t ARENA = (size_t)BB * N_GO * FF;
    float* P0 = (float*)alloc(ARENA * 4);
    float* P1 = (float*)alloc(ARENA * 4);
    float* P2 = (float*)alloc(ARENA * 4);
    float* P3 = (float*)alloc(ARENA * 4);
    float* EDGEV = (float*)alloc((size_t)BB * E0 * 4);
    float* ASRC = (float*)alloc((size_t)BB * N_GO * 4);
    float* ADST = (float*)alloc((size_t)BB * N_GO * 4);
    float* VS   = (float*)alloc((size_t)BB * N_GO * 4);
    float* SUMS = (float*)alloc(2 * BB * FF * 4);
    float* INP  = (float*)alloc((size_t)BB * N_LAST * 4);
    float* OUTD = (float*)alloc((size_t)BB * N_GO * 4);
    float* H1R  = (float*)alloc(BB * 32 * 4);
    float* DATAT = (float*)alloc((size_t)N_GENES * BB * 4);
    int* RS   = (int*)alloc(N_GO * 4);
    int* RE   = (int*)alloc(N_GO * 4);
    int* DEGI = (int*)alloc(N_GENES * 4);
    int* RSD  = (int*)alloc((N_GENES + 1) * 4);
    int* CURS = (int*)alloc(N_GENES * 4);
    int* CSRD = (int*)alloc((size_t)EDMAX * 4);      // dec CSR dst / gene CSR row
    float* CSRT = (float*)alloc((size_t)nnz * 4);    // gene CSR tD

    float* out_lat = (float*)d_out;                 // (B,16)
    float* out_xd  = out_lat + BB * L_DIM;          // (B,20000)
    float* out_att = out_xd + (size_t)BB * N_GENES; // (B,4000,5)

    dim3 blk(256);
    auto g1 = [](long n) { return dim3((unsigned)((n + 255) / 256)); };
    auto g2 = [](long n, int y) { return dim3((unsigned)((n + 255) / 256), (unsigned)y); };
    auto gw = [](int n) { return dim3((unsigned)((n + 3) / 4)); };  // wave-per-row
    const int LNB = 1024;
    const int LWAVES = LNB * 4;
    const int ANB = 256;                  // per-batch blocks for XCD-pinned agg
    const int N1 = N_GO - P0_; // 8000

    // ---- stage 0: gene -> GO ----
    k_tr_data<<<g1(N_GENES * BB), blk, 0, stream>>>(data, DATAT);
    k_bounds_bs<<<g1(N_GO), blk, 0, stream>>>(Ag_row, RS, RE, nnz, N_GO);
    k_gene2go_w<<<gw(N_GO), blk, 0, stream>>>(DATAT, t, Ag_col, RS, RE, P0, nnz);

    // ---- encoder 0 (n=12000) ----
    k_linear2_att8<true><<<dim3(LNB), blk, 0, stream>>>(P0, w_inc0, w_s0, w_att_in0, w_att_s0,
        P1, P2, ASRC, ADST, VS, N_GO, (long)N_GO * IN_F, 0, LWAVES);
    k_bounds_bs<<<g1(N_GO), blk, 0, stream>>>(enc_src0, RS, RE, E0, N_GO);
    k_edge_v<<<g2(E0, BB), blk, 0, stream>>>(ASRC, ADST, enc_src0, enc_dst0, EDGEV, E0, N_GO);
    hipMemsetAsync(SUMS, 0, 2 * BB * FF * 4, stream);
    k_agg_enc_f<<<dim3(ANB * 8), blk, 0, stream>>>(P1, P2, EDGEV, VS, enc_dst0, RS, RE, P3, SUMS, N_GO, E0, ANB);
    k_ln_apply_relu<<<g2((long)N_GO * FF, BB), blk, 0, stream>>>(P3, SUMS, gb_g0, gb_b0, P0, N_GO, FF);

    // ---- encoder 1 (n=8000, x = P0[:,4000:,:]) ----
    k_lin64d<true><<<dim3(LNB), blk, 0, stream>>>(P0, w_inc1, w_s1, w_att_in1, w_att_s1,
        P1, P2, ASRC, ADST, VS, N1, (long)N_GO * FF, P0_, LWAVES);
    k_bounds_bs<<<g1(N1), blk, 0, stream>>>(enc_src1, RS, RE, E1, N1);
    k_edge_v<<<g2(E1, BB), blk, 0, stream>>>(ASRC, ADST, enc_src1, enc_dst1, EDGEV, E1, N1);
    hipMemsetAsync(SUMS, 0, 2 * BB * FF * 4, stream);
    k_agg_enc_f<<<dim3(ANB * 8), blk, 0, stream>>>(P1, P2, EDGEV, VS, enc_dst1, RS, RE, P3, SUMS, N1, E1, ANB);
    k_ln_apply_relu<<<g2((long)N1 * FF, BB), blk, 0, stream>>>(P3, SUMS, gb_g1, gb_b1, P0, N1, FF);

    // ---- heads (x = P0[:,4000:,:] of (B,8000,64)) ----
    k_heads<<<gw(N_LAST), blk, 0, stream>>>(P0, catt_w, conc_w, catt_bn_g, catt_bn_b,
                                            b_bn_g, b_bn_b, out_att, INP, (long)N1 * FF, P0_);

    // ---- decoder 0 (in n=4000 -> rows 8000), CSR gather ----
    k_lin64d<false><<<dim3(LNB), blk, 0, stream>>>(P0, w_out0, w_sout0, nullptr, nullptr,
        P1, P2, nullptr, nullptr, nullptr, N_LAST, (long)N1 * FF, P0_, LWAVES);
    hipMemsetAsync(DEGI, 0, 8000 * 4, stream);
    k_deg_i<<<g1(ED0), blk, 0, stream>>>(dec_src0, DEGI, ED0);
    k_scan<<<dim3(1), dim3(1024), 0, stream>>>(DEGI, RSD, CURS, 8000);
    k_scatter<<<g1(ED0), blk, 0, stream>>>(dec_src0, dec_dst0, CURS, CSRD, ED0);
    hipMemsetAsync(SUMS, 0, 2 * BB * FF * 4, stream);
    k_agg_dec64<<<dim3(ANB * 8), blk, 0, stream>>>(P1, P2, RSD, CSRD, P3, SUMS, 8000, N_LAST, 4000, ANB);
    k_ln_apply_relu<<<g2((long)8000 * FF, BB), blk, 0, stream>>>(P3, SUMS, gbd_g0, gbd_b0, P0, 8000, FF);

    // ---- decoder 1 (in n=8000 F=64 -> rows 12000 F=8), CSR gather ----
    k_lin8d<<<dim3(LNB), blk, 0, stream>>>(P0, w_out1, w_sout1, P1, P2, 8000, (long)8000 * FF, 0, LWAVES);
    hipMemsetAsync(DEGI, 0, N_GO * 4, stream);
    k_deg_i<<<g1(ED1), blk, 0, stream>>>(dec_src1, DEGI, ED1);
    k_scan<<<dim3(1), dim3(1024), 0, stream>>>(DEGI, RSD, CURS, N_GO);
    k_scatter<<<g1(ED1), blk, 0, stream>>>(dec_src1, dec_dst1, CURS, CSRD, ED1);
    k_agg_dec8<<<gw(N_GO), blk, 0, stream>>>(P1, P2, RSD, CSRD, P3, N_GO, 8000, 4000);
    hipMemsetAsync(SUMS, 0, 2 * BB * IN_F * 4, stream);
    k_ln_stats<<<dim3((N_GO + 511) / 512, BB), blk, 0, stream>>>(P3, SUMS, N_GO, IN_F, 512);
    k_ln_apply_relu<<<g2((long)N_GO * IN_F, BB), blk, 0, stream>>>(P3, SUMS, gbd_g1, gbd_b1, P0, N_GO, IN_F);

    // ---- out_D head + x_D gather (column-CSR of Ag) ----
    k_head_scalar<IN_F><<<g1(N_GO), blk, 0, stream>>>(P0, concd_w, bd_bn_g, bd_bn_b, OUTD, N_GO, (long)N_GO * IN_F, 0);
    hipMemsetAsync(DEGI, 0, N_GENES * 4, stream);
    k_deg_i<<<g1(nnz), blk, 0, stream>>>(Ag_col, DEGI, nnz);
    k_scan<<<dim3(1), dim3(1024), 0, stream>>>(DEGI, RSD, CURS, N_GENES);
    k_scatter2<<<g1(nnz), blk, 0, stream>>>(Ag_col, Ag_row, t_D, CURS, CSRD, CSRT, nnz);
    k_xd_g<<<gw(N_GENES), blk, 0, stream>>>(OUTD, RSD, CSRD, CSRT, out_xd);

    // ---- latent MLP (fused) ----
    k_lat1<<<dim3(32), dim3(512), 0, stream>>>(INP, lat_w1, lat_bn1_g, lat_bn1_b, H1R);
    k_lat2<<<dim3(1), dim3(128), 0, stream>>>(H1R, lat_w2, lat_bn2_g, lat_bn2_b, out_lat);

    (void)n_in; (void)out_size; (void)ws_size;
}